// Round 5
// baseline (282.194 us; speedup 1.0000x reference)
//
#include <hip/hip_runtime.h>
#include <math.h>

#define NB 8192
#define G 4                 // batch rows per block
#define NBLK (NB / G)
#define NNODES 32
#define TT 3
#define DIM 128
#define HID 128
#define USTR 132            // uvL padded stride (floats): 16B-aligned rows, bank rotation 4/row

// Kernel 1: uv[e][d], e<9: u[i=e/3][j=e%3][d] = W[i] row d . a_top[j]
//           e=9+t:    v[t][d]                 = W[t] row d . a_bot[t]
// Identical for all batch rows -> compute ONCE into d_ws (ws validated earlier).
__global__ __launch_bounds__(128) void gat_prep(
    const float* __restrict__ Wg,   // (3,128,128) fp32
    const float* __restrict__ ag,   // (3,256,1)   fp32
    float* __restrict__ uv)         // (12,128)    fp32
{
    int e = blockIdx.x, d = threadIdx.x;
    int wi, aoff;
    if (e < 9) { wi = e / 3; aoff = (e % 3) * 2 * HID; }        // a_top[j]
    else       { wi = e - 9; aoff = wi * 2 * HID + HID; }       // a_bot[t]
    const float* wrow = Wg + wi * DIM * HID + d * HID;
    const float* arow = ag + aoff;
    float acc = 0.f;
    #pragma unroll 16
    for (int h = 0; h < HID; ++h) acc += wrow[h] * arow[h];
    uv[e * DIM + d] = acc;
}

// Chunk (n, c) of a 32x128 fp32 row-tile lives at float4-slot n*32 + (c ^ (n&7)).
// XOR is an involution: global_load_lds writes LINEAR dest slots while each lane
// reads the pre-swizzled global source chunk; LDS readers apply the same XOR.
__device__ __forceinline__ int swz_slot(int n, int c) { return n * 32 + (c ^ (n & 7)); }

// LDS-only barrier: drains lgkmcnt but NOT vmcnt, so in-flight global_load_lds
// DMA (tracked by vmcnt) keeps running across the barrier.
__device__ __forceinline__ void lds_barrier() {
    asm volatile("s_waitcnt lgkmcnt(0)" ::: "memory");
    __builtin_amdgcn_s_barrier();
}

// Stage one 16 KB h-row into LDS via direct global->LDS DMA (no VGPR staging).
// Linear LDS dest (wave-uniform base + lane*16), per-lane pre-swizzled source.
__device__ __forceinline__ void stage_row(const float* __restrict__ hrow,
                                          float* lbuf, int tid) {
    const int wv = tid >> 6, lane = tid & 63;
    #pragma unroll
    for (int k = 0; k < 4; ++k) {
        int s = wv * 256 + k * 64 + lane;          // linear dest float4-slot
        int n = s >> 5, c = s & 31;
        const float4* g = (const float4*)hrow + (n * 32 + (c ^ (n & 7)));
        float4* l = (float4*)lbuf + (wv * 256 + k * 64);   // wave-uniform base
        __builtin_amdgcn_global_load_lds(
            (const __attribute__((address_space(1))) void*)g,
            (__attribute__((address_space(3))) void*)l, 16, 0, 0);
    }
}

__global__ __launch_bounds__(256, 4) void gat_main(
    const float* __restrict__ hg,     // (B,32,128) fp32
    const int* __restrict__ maskg,    // (3,B,32) 4-byte bool words
    const float* __restrict__ Wg,     // (3,128,128) fp32
    const float* __restrict__ uv,     // (12,128) fp32 (from d_ws)
    float* __restrict__ outg)         // (B,128) fp32
{
    __shared__ __align__(16) float hL[2 * NNODES * DIM];  // 32 KB dbuf h row (swizzled); reused post-loop
    __shared__ __align__(16) float uvL[12 * USTR];        // 6,336 B
    __shared__ float sTop[16];                            // [3i+j]
    __shared__ __align__(16) float sNbT[NNODES * 4];      // [node][t0,t1,t2,pad] scores->weights
    __shared__ unsigned char mvB[G * 96];                 // 384 B masks as bytes
    // total ~40,064 B -> 4 blocks/CU

    const int tid = threadIdx.x;
    const int b0 = blockIdx.x * G;
    const int dq = tid & 3;

    // ---- stage uv into LDS (1536 elems, 6/thread) ----
    #pragma unroll
    for (int k = 0; k < 6; ++k) {
        int i = tid + k * 256;
        uvL[(i >> 7) * USTR + (i & 127)] = uv[i];
    }
    // ---- prefetch all G rows' masks (as bytes) ----
    if (tid < 96) {
        int t = tid >> 5, node = tid & 31;
        #pragma unroll
        for (int g = 0; g < G; ++g)
            mvB[g * 96 + tid] = (unsigned char)(
                maskg[(size_t)t * NB * NNODES + (size_t)(b0 + g) * NNODES + node] ? 1 : 0);
    }

    // ---- initial stage: row b0 -> buffer 0 (DMA, swizzled source) ----
    stage_row(hg + (size_t)b0 * (NNODES * DIM), hL, tid);
    __syncthreads();    // drains vmcnt(0)+lgkmcnt(0): buf0, uvL, mvB all ready

    float4 grq[G];      // combine result: one float4 (4 d's) per thread per g, static idx

    #pragma unroll
    for (int g = 0; g < G; ++g) {
        const float* hb = hL + (g & 1) * (NNODES * DIM);

        // ---- issue DMA for row g+1 into the other buffer (waited at end of iter) ----
        if (g + 1 < G)
            stage_row(hg + (size_t)(b0 + g + 1) * (NNODES * DIM),
                      hL + ((g + 1) & 1) * (NNODES * DIM), tid);

        // ---- phase 1: 105 dots as (t, n-pair, d-quarter) tasks, u/v from uvL ----
        if (tid < 228) {
            const float4* hb4 = (const float4*)hb;
            if (tid < 192) {
                int task4 = tid >> 2;
                int t  = task4 >> 4;                 // == tid>>6, wave-uniform row
                int n0 = (task4 & 15) * 2;
                const float4* up = (const float4*)&uvL[(9 + t) * USTR];
                float a0 = 0.f, a1 = 0.f;
                #pragma unroll
                for (int k = 0; k < 8; ++k) {
                    int c = dq + 4 * k;
                    float4 x0 = hb4[swz_slot(n0,     c)];
                    float4 x1 = hb4[swz_slot(n0 + 1, c)];
                    float4 u  = up[c];
                    a0 += x0.x*u.x + x0.y*u.y + x0.z*u.z + x0.w*u.w;
                    a1 += x1.x*u.x + x1.y*u.y + x1.z*u.z + x1.w*u.w;
                }
                a0 += __shfl_xor(a0, 1, 64); a0 += __shfl_xor(a0, 2, 64);
                a1 += __shfl_xor(a1, 1, 64); a1 += __shfl_xor(a1, 2, 64);
                if (dq == 0) { sNbT[n0 * 4 + t] = a0; sNbT[(n0 + 1) * 4 + t] = a1; }
            } else {
                int e = (tid - 192) >> 2;   // 0..8, groups of 4 lanes (4-aligned, shfl-safe)
                const float4* up = (const float4*)&uvL[e * USTR];
                float a = 0.f;
                #pragma unroll
                for (int k = 0; k < 8; ++k) {
                    int c = dq + 4 * k;
                    float4 x = hb4[c];      // row 0: swizzle is identity
                    float4 u = up[c];
                    a += x.x*u.x + x.y*u.y + x.z*u.z + x.w*u.w;
                }
                a += __shfl_xor(a, 1, 64); a += __shfl_xor(a, 2, 64);
                if (dq == 0) sTop[e] = a;
            }
        }
        lds_barrier();

        // ---- phase 2: masked softmax (ally and opp separate) -> weights in-place in sNbT ----
        int wv = tid >> 6;
        if (wv == 0) {
            // ally: (j,n), 45 lanes; i collapsed (3 exps/lane)
            int lane = tid;
            bool act = lane < 45;
            int j = act ? lane / 15 : 0;
            int n = act ? lane % 15 : 0;
            int mk = 1; float sv = 0.f;
            if (act) {
                mk = mvB[g * 96 + j * 32 + 1 + n];
                sv = sNbT[(1 + n) * 4 + j];
            }
            float e0 = sTop[0 + j] + sv;
            float e1 = sTop[3 + j] + sv;
            float e2 = sTop[6 + j] + sv;
            bool live = act && (mk == 0);
            float lm = live ? fmaxf(e0, fmaxf(e1, e2)) : -__builtin_inff();
            #pragma unroll
            for (int off = 32; off; off >>= 1) lm = fmaxf(lm, __shfl_xor(lm, off, 64));
            float es = live ? (expf(e0 - lm) + expf(e1 - lm) + expf(e2 - lm)) : 0.f;
            float Z = es;
            #pragma unroll
            for (int off = 32; off; off >>= 1) Z += __shfl_xor(Z, off, 64);
            float w = (live && Z > 0.f) ? es / Z : 0.f;
            if (act) sNbT[(1 + n) * 4 + j] = w;
        } else if (wv == 1) {
            // opp: (j,n), 48 lanes
            int lane = tid - 64;
            bool act = lane < 48;
            int j = act ? (lane >> 4) : 0;
            int n = act ? (lane & 15) : 0;
            int mk = 1; float sv = 0.f;
            if (act) {
                mk = mvB[g * 96 + j * 32 + 16 + n];
                sv = sNbT[(16 + n) * 4 + j];
            }
            float e0 = sTop[0 + j] + sv;
            float e1 = sTop[3 + j] + sv;
            float e2 = sTop[6 + j] + sv;
            bool live = act && (mk == 0);
            float lm = live ? fmaxf(e0, fmaxf(e1, e2)) : -__builtin_inff();
            #pragma unroll
            for (int off = 32; off; off >>= 1) lm = fmaxf(lm, __shfl_xor(lm, off, 64));
            float es = live ? (expf(e0 - lm) + expf(e1 - lm) + expf(e2 - lm)) : 0.f;
            float Z = es;
            #pragma unroll
            for (int off = 32; off; off >>= 1) Z += __shfl_xor(Z, off, 64);
            float w = (live && Z > 0.f) ? es / Z : 0.f;
            if (act) sNbT[(16 + n) * 4 + j] = w;
        } else if (wv == 2) {
            int lane = tid - 128;
            if (lane < 3)
                sNbT[0 * 4 + lane] = mvB[g * 96 + lane * 32 + 0] ? 1.f : 0.f; // self: True -> included
        }
        lds_barrier();

        // ---- combine: (q=d-quad, sub=n-subset) split, all-b128 reads,
        //      4-lane shuffle reduce; result float4 kept in grq[g] ----
        if (tid < 128) {
            int q = tid >> 2;       // d-quad 0..31
            int sub = tid & 3;      // n-subset
            const float4* hb4 = (const float4*)hb;
            const float4* wq4 = (const float4*)sNbT;
            float4 A0 = make_float4(0.f, 0.f, 0.f, 0.f);
            float4 A1 = make_float4(0.f, 0.f, 0.f, 0.f);
            float4 A2 = make_float4(0.f, 0.f, 0.f, 0.f);
            #pragma unroll
            for (int i = 0; i < 8; ++i) {
                int n = sub + 4 * i;
                float4 hv = hb4[swz_slot(n, q)];
                float4 w  = wq4[n];                // (w[t0],w[t1],w[t2],pad)
                A0.x += w.x * hv.x; A0.y += w.x * hv.y; A0.z += w.x * hv.z; A0.w += w.x * hv.w;
                A1.x += w.y * hv.x; A1.y += w.y * hv.y; A1.z += w.y * hv.z; A1.w += w.y * hv.w;
                A2.x += w.z * hv.x; A2.y += w.z * hv.y; A2.z += w.z * hv.z; A2.w += w.z * hv.w;
            }
            // reduce across the 4-lane n-subset group (lanes 4k..4k+3)
            #pragma unroll
            for (int off = 1; off <= 2; off <<= 1) {
                A0.x += __shfl_xor(A0.x, off, 64); A0.y += __shfl_xor(A0.y, off, 64);
                A0.z += __shfl_xor(A0.z, off, 64); A0.w += __shfl_xor(A0.w, off, 64);
                A1.x += __shfl_xor(A1.x, off, 64); A1.y += __shfl_xor(A1.y, off, 64);
                A1.z += __shfl_xor(A1.z, off, 64); A1.w += __shfl_xor(A1.w, off, 64);
                A2.x += __shfl_xor(A2.x, off, 64); A2.y += __shfl_xor(A2.y, off, 64);
                A2.z += __shfl_xor(A2.z, off, 64); A2.w += __shfl_xor(A2.w, off, 64);
            }
            // lane sub holds t=sub's quad (sub==3 unused)
            grq[g] = (sub == 1) ? A1 : ((sub == 2) ? A2 : A0);
        }

        // ---- end of iter: wait for prefetch DMA + all LDS ops, then barrier ----
        asm volatile("s_waitcnt vmcnt(0) lgkmcnt(0)" ::: "memory");
        __builtin_amdgcn_s_barrier();
    }

    // ---- dump grq into dead hL as gA: float4 slot g*96 + t*32 + q ----
    if (tid < 128 && (tid & 3) < 3) {
        int q = tid >> 2, t = tid & 3;
        #pragma unroll
        for (int g = 0; g < G; ++g)
            ((float4*)hL)[g * 96 + t * 32 + q] = grq[g];
    }
    __syncthreads();

    // ---- epilogue: out[b0+g][h] = sum_t sum_d gA[g][t][d] * W[t][d][h] ----
    // 256 threads = 32 h-quads x 8 d-groups of 16; W streamed once per block (float4);
    // gA read as b128 (4 d's at a time).
    {
        int hq  = tid & 31;          // h0 = 4*hq
        int dq8 = tid >> 5;          // 0..7
        const float4* gA4 = (const float4*)hL;
        float4 acc[G];
        #pragma unroll
        for (int g = 0; g < G; ++g) acc[g] = make_float4(0.f, 0.f, 0.f, 0.f);
        #pragma unroll
        for (int t = 0; t < TT; ++t) {
            const float4* wb = (const float4*)(Wg + ((size_t)t * DIM + dq8 * 16) * HID) + hq;
            #pragma unroll
            for (int dp = 0; dp < 4; ++dp) {
                float4 w0 = wb[(dp * 4 + 0) * 32];
                float4 w1 = wb[(dp * 4 + 1) * 32];
                float4 w2 = wb[(dp * 4 + 2) * 32];
                float4 w3 = wb[(dp * 4 + 3) * 32];
                #pragma unroll
                for (int g = 0; g < G; ++g) {
                    float4 gv = gA4[g * 96 + t * 32 + dq8 * 4 + dp];  // 2-addr broadcast
                    acc[g].x += gv.x * w0.x + gv.y * w1.x + gv.z * w2.x + gv.w * w3.x;
                    acc[g].y += gv.x * w0.y + gv.y * w1.y + gv.z * w2.y + gv.w * w3.y;
                    acc[g].z += gv.x * w0.z + gv.y * w1.z + gv.z * w2.z + gv.w * w3.z;
                    acc[g].w += gv.x * w0.w + gv.y * w1.w + gv.z * w2.w + gv.w * w3.w;
                }
            }
        }
        // partials into hL floats 2048..6143 (float4 slot (dq8*4+g)*32 + hq)
        float4* pL4 = (float4*)(hL + 2048);
        #pragma unroll
        for (int g = 0; g < G; ++g)
            pL4[(dq8 * 4 + g) * 32 + hq] = acc[g];
    }
    __syncthreads();

    // ---- final: reduce 8 partials (b128), ELU, float4 store ----
    if (tid < 128) {
        int g = tid >> 5, q = tid & 31;
        const float4* pL4 = (const float4*)(hL + 2048);
        float4 s = make_float4(0.f, 0.f, 0.f, 0.f);
        #pragma unroll
        for (int p = 0; p < 8; ++p) {
            float4 v = pL4[p * 128 + g * 32 + q];
            s.x += v.x; s.y += v.y; s.z += v.z; s.w += v.w;
        }
        s.x = (s.x > 0.f) ? s.x : expm1f(s.x);
        s.y = (s.y > 0.f) ? s.y : expm1f(s.y);
        s.z = (s.z > 0.f) ? s.z : expm1f(s.z);
        s.w = (s.w > 0.f) ? s.w : expm1f(s.w);
        ((float4*)outg)[(size_t)(b0 + g) * 32 + q] = s;
    }
}

extern "C" void kernel_launch(void* const* d_in, const int* in_sizes, int n_in,
                              void* d_out, int out_size, void* d_ws, size_t ws_size,
                              hipStream_t stream) {
    const float* hg    = (const float*)d_in[0];    // h (B,32,128) fp32
    const int*   maskg = (const int*)d_in[1];      // ALL_TYPE_MASK (3,B,32) 4-byte words
    // d_in[2]=num_ally, d_in[3]=num_opp, d_in[4]=self_type (fixed)
    const float* Wg    = (const float*)d_in[5];    // W (3,128,128) fp32
    const float* ag    = (const float*)d_in[6];    // a (3,256,1) fp32
    float* uv = (float*)d_ws;                      // 12*128 fp32 scratch (validated)
    float* outg = (float*)d_out;                   // fp32 output

    gat_prep<<<12, 128, 0, stream>>>(Wg, ag, uv);
    gat_main<<<NBLK, 256, 0, stream>>>(hg, maskg, Wg, uv, outg);
}

// Round 6
// 270.503 us; speedup vs baseline: 1.0432x; 1.0432x over previous
//
#include <hip/hip_runtime.h>
#include <math.h>

#define NB 8192
#define G 4                 // batch rows per block
#define NBLK (NB / G)
#define NNODES 32
#define TT 3
#define DIM 128
#define HID 128
#define USTR 132            // uvL padded stride (floats): 16B-aligned rows, bank rotation 4/row

// Kernel 1: uv[e][d], e<9: u[i=e/3][j=e%3][d] = W[i] row d . a_top[j]
//           e=9+t:    v[t][d]                 = W[t] row d . a_bot[t]
// Identical for all batch rows -> compute ONCE into d_ws (ws validated earlier).
__global__ __launch_bounds__(128) void gat_prep(
    const float* __restrict__ Wg,   // (3,128,128) fp32
    const float* __restrict__ ag,   // (3,256,1)   fp32
    float* __restrict__ uv)         // (12,128)    fp32
{
    int e = blockIdx.x, d = threadIdx.x;
    int wi, aoff;
    if (e < 9) { wi = e / 3; aoff = (e % 3) * 2 * HID; }        // a_top[j]
    else       { wi = e - 9; aoff = wi * 2 * HID + HID; }       // a_bot[t]
    const float* wrow = Wg + wi * DIM * HID + d * HID;
    const float* arow = ag + aoff;
    float acc = 0.f;
    #pragma unroll 16
    for (int h = 0; h < HID; ++h) acc += wrow[h] * arow[h];
    uv[e * DIM + d] = acc;
}

// Chunk (n, c) of a 32x128 fp32 row-tile lives at float4-slot n*32 + (c ^ (n&7)).
// XOR is an involution: global_load_lds writes LINEAR dest slots while each lane
// reads the pre-swizzled global source chunk; LDS readers apply the same XOR.
__device__ __forceinline__ int swz_slot(int n, int c) { return n * 32 + (c ^ (n & 7)); }

// LDS-only barrier: drains lgkmcnt but NOT vmcnt, so in-flight global_load_lds
// DMA (tracked by vmcnt) keeps running across the barrier.
__device__ __forceinline__ void lds_barrier() {
    asm volatile("s_waitcnt lgkmcnt(0)" ::: "memory");
    __builtin_amdgcn_s_barrier();
}

// Stage one 16 KB h-row into LDS via direct global->LDS DMA (no VGPR staging).
// Linear LDS dest (wave-uniform base + lane*16), per-lane pre-swizzled source.
__device__ __forceinline__ void stage_row(const float* __restrict__ hrow,
                                          float* lbuf, int tid) {
    const int wv = tid >> 6, lane = tid & 63;
    #pragma unroll
    for (int k = 0; k < 4; ++k) {
        int s = wv * 256 + k * 64 + lane;          // linear dest float4-slot
        int n = s >> 5, c = s & 31;
        const float4* g = (const float4*)hrow + (n * 32 + (c ^ (n & 7)));
        float4* l = (float4*)lbuf + (wv * 256 + k * 64);   // wave-uniform base
        __builtin_amdgcn_global_load_lds(
            (const __attribute__((address_space(1))) void*)g,
            (__attribute__((address_space(3))) void*)l, 16, 0, 0);
    }
}

__global__ __launch_bounds__(256, 4) void gat_main(
    const float* __restrict__ hg,     // (B,32,128) fp32
    const int* __restrict__ maskg,    // (3,B,32) 4-byte bool words
    const float* __restrict__ Wg,     // (3,128,128) fp32
    const float* __restrict__ uv,     // (12,128) fp32 (from d_ws)
    float* __restrict__ outg)         // (B,128) fp32
{
    __shared__ __align__(16) float hL[2 * NNODES * DIM];  // 32 KB dbuf h row (swizzled); reused post-loop
    __shared__ __align__(16) float uvL[12 * USTR];        // 6,336 B
    __shared__ float sTop[16];                            // [3i+j]
    __shared__ __align__(16) float sNbT[NNODES * 4];      // [node][t0,t1,t2,pad] scores->weights
    __shared__ unsigned char mvB[G * 96];                 // 384 B masks as bytes
    // total ~40,064 B -> 4 blocks/CU

    const int tid = threadIdx.x;
    const int b0 = blockIdx.x * G;
    const int dq = tid & 3;

    // ---- stage uv into LDS (1536 elems, 6/thread) ----
    #pragma unroll
    for (int k = 0; k < 6; ++k) {
        int i = tid + k * 256;
        uvL[(i >> 7) * USTR + (i & 127)] = uv[i];
    }
    // ---- prefetch all G rows' masks (as bytes) ----
    if (tid < 96) {
        int t = tid >> 5, node = tid & 31;
        #pragma unroll
        for (int g = 0; g < G; ++g)
            mvB[g * 96 + tid] = (unsigned char)(
                maskg[(size_t)t * NB * NNODES + (size_t)(b0 + g) * NNODES + node] ? 1 : 0);
    }

    // ---- initial stage: row b0 -> buffer 0 (DMA, swizzled source) ----
    stage_row(hg + (size_t)b0 * (NNODES * DIM), hL, tid);
    __syncthreads();    // drains vmcnt(0)+lgkmcnt(0): buf0, uvL, mvB all ready

    float gr[G][TT];    // combine accumulators: 12 scalars, statically indexed (proven no-spill)

    #pragma unroll
    for (int g = 0; g < G; ++g) {
        const float* hb = hL + (g & 1) * (NNODES * DIM);

        // ---- issue DMA for row g+1 into the other buffer (waited at end of iter) ----
        if (g + 1 < G)
            stage_row(hg + (size_t)(b0 + g + 1) * (NNODES * DIM),
                      hL + ((g + 1) & 1) * (NNODES * DIM), tid);

        // ---- phase 1: 105 dots as (t, n-pair, d-quarter) tasks, u/v from uvL ----
        if (tid < 228) {
            const float4* hb4 = (const float4*)hb;
            if (tid < 192) {
                int task4 = tid >> 2;
                int t  = task4 >> 4;                 // == tid>>6, wave-uniform row
                int n0 = (task4 & 15) * 2;
                const float4* up = (const float4*)&uvL[(9 + t) * USTR];
                float a0 = 0.f, a1 = 0.f;
                #pragma unroll
                for (int k = 0; k < 8; ++k) {
                    int c = dq + 4 * k;
                    float4 x0 = hb4[swz_slot(n0,     c)];
                    float4 x1 = hb4[swz_slot(n0 + 1, c)];
                    float4 u  = up[c];
                    a0 += x0.x*u.x + x0.y*u.y + x0.z*u.z + x0.w*u.w;
                    a1 += x1.x*u.x + x1.y*u.y + x1.z*u.z + x1.w*u.w;
                }
                a0 += __shfl_xor(a0, 1, 64); a0 += __shfl_xor(a0, 2, 64);
                a1 += __shfl_xor(a1, 1, 64); a1 += __shfl_xor(a1, 2, 64);
                if (dq == 0) { sNbT[n0 * 4 + t] = a0; sNbT[(n0 + 1) * 4 + t] = a1; }
            } else {
                int e = (tid - 192) >> 2;   // 0..8, groups of 4 lanes (4-aligned, shfl-safe)
                const float4* up = (const float4*)&uvL[e * USTR];
                float a = 0.f;
                #pragma unroll
                for (int k = 0; k < 8; ++k) {
                    int c = dq + 4 * k;
                    float4 x = hb4[c];      // row 0: swizzle is identity
                    float4 u = up[c];
                    a += x.x*u.x + x.y*u.y + x.z*u.z + x.w*u.w;
                }
                a += __shfl_xor(a, 1, 64); a += __shfl_xor(a, 2, 64);
                if (dq == 0) sTop[e] = a;
            }
        }
        lds_barrier();

        // ---- phase 2: masked softmax (ally and opp separate) -> weights in-place in sNbT ----
        int wv = tid >> 6;
        if (wv == 0) {
            // ally: (j,n), 45 lanes; i collapsed (3 exps/lane)
            int lane = tid;
            bool act = lane < 45;
            int j = act ? lane / 15 : 0;
            int n = act ? lane % 15 : 0;
            int mk = 1; float sv = 0.f;
            if (act) {
                mk = mvB[g * 96 + j * 32 + 1 + n];
                sv = sNbT[(1 + n) * 4 + j];
            }
            float e0 = sTop[0 + j] + sv;
            float e1 = sTop[3 + j] + sv;
            float e2 = sTop[6 + j] + sv;
            bool live = act && (mk == 0);
            float lm = live ? fmaxf(e0, fmaxf(e1, e2)) : -__builtin_inff();
            #pragma unroll
            for (int off = 32; off; off >>= 1) lm = fmaxf(lm, __shfl_xor(lm, off, 64));
            float es = live ? (expf(e0 - lm) + expf(e1 - lm) + expf(e2 - lm)) : 0.f;
            float Z = es;
            #pragma unroll
            for (int off = 32; off; off >>= 1) Z += __shfl_xor(Z, off, 64);
            float w = (live && Z > 0.f) ? es / Z : 0.f;
            if (act) sNbT[(1 + n) * 4 + j] = w;
        } else if (wv == 1) {
            // opp: (j,n), 48 lanes
            int lane = tid - 64;
            bool act = lane < 48;
            int j = act ? (lane >> 4) : 0;
            int n = act ? (lane & 15) : 0;
            int mk = 1; float sv = 0.f;
            if (act) {
                mk = mvB[g * 96 + j * 32 + 16 + n];
                sv = sNbT[(16 + n) * 4 + j];
            }
            float e0 = sTop[0 + j] + sv;
            float e1 = sTop[3 + j] + sv;
            float e2 = sTop[6 + j] + sv;
            bool live = act && (mk == 0);
            float lm = live ? fmaxf(e0, fmaxf(e1, e2)) : -__builtin_inff();
            #pragma unroll
            for (int off = 32; off; off >>= 1) lm = fmaxf(lm, __shfl_xor(lm, off, 64));
            float es = live ? (expf(e0 - lm) + expf(e1 - lm) + expf(e2 - lm)) : 0.f;
            float Z = es;
            #pragma unroll
            for (int off = 32; off; off >>= 1) Z += __shfl_xor(Z, off, 64);
            float w = (live && Z > 0.f) ? es / Z : 0.f;
            if (act) sNbT[(16 + n) * 4 + j] = w;
        } else if (wv == 2) {
            int lane = tid - 128;
            if (lane < 3)
                sNbT[0 * 4 + lane] = mvB[g * 96 + lane * 32 + 0] ? 1.f : 0.f; // self: True -> included
        }
        lds_barrier();

        // ---- combine into registers: gr[g][t] for d = tid; weights via b128 broadcast ----
        if (tid < 128) {
            int d = tid;
            int chi = d >> 2, clo = d & 3;
            const float4* wq4 = (const float4*)sNbT;
            float a0 = 0.f, a1 = 0.f, a2 = 0.f;
            #pragma unroll
            for (int n = 0; n < NNODES; ++n) {
                float hv = hb[n * DIM + ((chi ^ (n & 7)) << 2) + clo];
                float4 w = wq4[n];          // wave-uniform -> b128 broadcast, 1 inst / 3 weights
                a0 += w.x * hv;
                a1 += w.y * hv;
                a2 += w.z * hv;
            }
            gr[g][0] = a0; gr[g][1] = a1; gr[g][2] = a2;
        }

        // ---- end of iter: wait for prefetch DMA + all LDS ops, then barrier ----
        asm volatile("s_waitcnt vmcnt(0) lgkmcnt(0)" ::: "memory");
        __builtin_amdgcn_s_barrier();
    }

    // ---- dump gr into dead hL buffer 0: gA[g*384 + t*128 + d] (floats 0..1535) ----
    if (tid < 128) {
        #pragma unroll
        for (int g = 0; g < G; ++g) {
            hL[g * 384 + 0 * 128 + tid] = gr[g][0];
            hL[g * 384 + 1 * 128 + tid] = gr[g][1];
            hL[g * 384 + 2 * 128 + tid] = gr[g][2];
        }
    }
    __syncthreads();

    // ---- epilogue: out[b0+g][h] = sum_t sum_d gA[g][t][d] * W[t][d][h] ----
    // 256 threads = 32 h-quads x 8 d-groups of 16; W streamed once per block (float4);
    // gA read as b128 (4 d's at a time).
    {
        int hq  = tid & 31;          // h0 = 4*hq
        int dq8 = tid >> 5;          // 0..7
        const float4* gA4 = (const float4*)hL;   // gA[g][t][d] float4 slot = g*96 + t*32 + d/4
        float4 acc[G];
        #pragma unroll
        for (int g = 0; g < G; ++g) acc[g] = make_float4(0.f, 0.f, 0.f, 0.f);
        #pragma unroll
        for (int t = 0; t < TT; ++t) {
            const float4* wb = (const float4*)(Wg + ((size_t)t * DIM + dq8 * 16) * HID) + hq;
            #pragma unroll
            for (int dp = 0; dp < 4; ++dp) {
                float4 w0 = wb[(dp * 4 + 0) * 32];
                float4 w1 = wb[(dp * 4 + 1) * 32];
                float4 w2 = wb[(dp * 4 + 2) * 32];
                float4 w3 = wb[(dp * 4 + 3) * 32];
                #pragma unroll
                for (int g = 0; g < G; ++g) {
                    float4 gv = gA4[g * 96 + t * 32 + dq8 * 4 + dp];  // b128 broadcast
                    acc[g].x += gv.x * w0.x + gv.y * w1.x + gv.z * w2.x + gv.w * w3.x;
                    acc[g].y += gv.x * w0.y + gv.y * w1.y + gv.z * w2.y + gv.w * w3.y;
                    acc[g].z += gv.x * w0.z + gv.y * w1.z + gv.z * w2.z + gv.w * w3.z;
                    acc[g].w += gv.x * w0.w + gv.y * w1.w + gv.z * w2.w + gv.w * w3.w;
                }
            }
        }
        // partials into hL floats 2048..6143 (float4 slot (dq8*4+g)*32 + hq)
        float4* pL4 = (float4*)(hL + 2048);
        #pragma unroll
        for (int g = 0; g < G; ++g)
            pL4[(dq8 * 4 + g) * 32 + hq] = acc[g];
    }
    __syncthreads();

    // ---- final: reduce 8 partials (b128), ELU, float4 store ----
    if (tid < 128) {
        int g = tid >> 5, q = tid & 31;
        const float4* pL4 = (const float4*)(hL + 2048);
        float4 s = make_float4(0.f, 0.f, 0.f, 0.f);
        #pragma unroll
        for (int p = 0; p < 8; ++p) {
            float4 v = pL4[p * 128 + g * 32 + q];
            s.x += v.x; s.y += v.y; s.z += v.z; s.w += v.w;
        }
        s.x = (s.x > 0.f) ? s.x : expm1f(s.x);
        s.y = (s.y > 0.f) ? s.y : expm1f(s.y);
        s.z = (s.z > 0.f) ? s.z : expm1f(s.z);
        s.w = (s.w > 0.f) ? s.w : expm1f(s.w);
        ((float4*)outg)[(size_t)(b0 + g) * 32 + q] = s;
    }
}

extern "C" void kernel_launch(void* const* d_in, const int* in_sizes, int n_in,
                              void* d_out, int out_size, void* d_ws, size_t ws_size,
                              hipStream_t stream) {
    const float* hg    = (const float*)d_in[0];    // h (B,32,128) fp32
    const int*   maskg = (const int*)d_in[1];      // ALL_TYPE_MASK (3,B,32) 4-byte words
    // d_in[2]=num_ally, d_in[3]=num_opp, d_in[4]=self_type (fixed)
    const float* Wg    = (const float*)d_in[5];    // W (3,128,128) fp32
    const float* ag    = (const float*)d_in[6];    // a (3,256,1) fp32
    float* uv = (float*)d_ws;                      // 12*128 fp32 scratch (validated)
    float* outg = (float*)d_out;                   // fp32 output

    gat_prep<<<12, 128, 0, stream>>>(Wg, ag, uv);
    gat_main<<<NBLK, 256, 0, stream>>>(hg, maskg, Wg, uv, outg);
}

// Round 7
// 237.425 us; speedup vs baseline: 1.1886x; 1.1393x over previous
//
#include <hip/hip_runtime.h>
#include <math.h>

#define NB 8192
#define G 4                 // batch rows per block
#define NBLK (NB / G)
#define NNODES 32
#define TT 3
#define DIM 128
#define HID 128
#define USTR 132            // uvL padded stride (floats): 16B-aligned rows, bank rotation 4/row

// Kernel 1: uv[e][d], e<9: u[i=e/3][j=e%3][d] = W[i] row d . a_top[j]
//           e=9+t:    v[t][d]                 = W[t] row d . a_bot[t]
// Identical for all batch rows -> compute ONCE into d_ws (ws validated earlier).
__global__ __launch_bounds__(128) void gat_prep(
    const float* __restrict__ Wg,   // (3,128,128) fp32
    const float* __restrict__ ag,   // (3,256,1)   fp32
    float* __restrict__ uv)         // (12,128)    fp32
{
    int e = blockIdx.x, d = threadIdx.x;
    int wi, aoff;
    if (e < 9) { wi = e / 3; aoff = (e % 3) * 2 * HID; }        // a_top[j]
    else       { wi = e - 9; aoff = wi * 2 * HID + HID; }       // a_bot[t]
    const float* wrow = Wg + wi * DIM * HID + d * HID;
    const float* arow = ag + aoff;
    float acc = 0.f;
    #pragma unroll 16
    for (int h = 0; h < HID; ++h) acc += wrow[h] * arow[h];
    uv[e * DIM + d] = acc;
}

// Chunk (n, c) of a 32x128 fp32 row-tile lives at float4-slot n*32 + (c ^ (n&7)).
// XOR is an involution: global_load_lds writes LINEAR dest slots while each lane
// reads the pre-swizzled global source chunk; LDS readers apply the same XOR.
__device__ __forceinline__ int swz_slot(int n, int c) { return n * 32 + (c ^ (n & 7)); }

// LDS-only barrier: drains lgkmcnt but NOT vmcnt, so in-flight global_load_lds
// DMA (tracked by vmcnt) keeps running across the barrier.
__device__ __forceinline__ void lds_barrier() {
    asm volatile("s_waitcnt lgkmcnt(0)" ::: "memory");
    __builtin_amdgcn_s_barrier();
}

// Stage one 16 KB h-row into LDS via direct global->LDS DMA (no VGPR staging).
// Linear LDS dest (wave-uniform base + lane*16), per-lane pre-swizzled source.
__device__ __forceinline__ void stage_row(const float* __restrict__ hrow,
                                          float* lbuf, int tid) {
    const int wv = tid >> 6, lane = tid & 63;
    #pragma unroll
    for (int k = 0; k < 4; ++k) {
        int s = wv * 256 + k * 64 + lane;          // linear dest float4-slot
        int n = s >> 5, c = s & 31;
        const float4* g = (const float4*)hrow + (n * 32 + (c ^ (n & 7)));
        float4* l = (float4*)lbuf + (wv * 256 + k * 64);   // wave-uniform base
        __builtin_amdgcn_global_load_lds(
            (const __attribute__((address_space(1))) void*)g,
            (__attribute__((address_space(3))) void*)l, 16, 0, 0);
    }
}

// launch_bounds (256, 2): LDS (40.4 KB) already caps occupancy at 4 blocks/CU
// (= 4 waves/SIMD, the 128-VGPR point). Demanding 4 waves/EU made the allocator
// defend a 64-VGPR/8-wave target that LDS makes unreachable -> 144 MB/dispatch
// scratch spill (rounds 2/5/6, all pinned at VGPR=64). min-waves=2 raises the
// cap to 256; expected allocation ~80-100 keeps 4 blocks/CU.
__global__ __launch_bounds__(256, 2) void gat_main(
    const float* __restrict__ hg,     // (B,32,128) fp32
    const int* __restrict__ maskg,    // (3,B,32) 4-byte bool words
    const float* __restrict__ Wg,     // (3,128,128) fp32
    const float* __restrict__ uv,     // (12,128) fp32 (from d_ws)
    float* __restrict__ outg)         // (B,128) fp32
{
    __shared__ __align__(16) float hL[2 * NNODES * DIM];  // 32 KB dbuf h row (swizzled); reused post-loop
    __shared__ __align__(16) float uvL[12 * USTR];        // 6,336 B
    __shared__ float sTop[16];                            // [3i+j]
    __shared__ __align__(16) float sNbT[NNODES * 4];      // [node][t0,t1,t2,pad] scores->weights
    __shared__ unsigned char mvB[G * 96];                 // 384 B masks as bytes
    // total ~40,064 B -> 4 blocks/CU

    const int tid = threadIdx.x;
    const int b0 = blockIdx.x * G;
    const int dq = tid & 3;

    // ---- stage uv into LDS (1536 elems, 6/thread) ----
    #pragma unroll
    for (int k = 0; k < 6; ++k) {
        int i = tid + k * 256;
        uvL[(i >> 7) * USTR + (i & 127)] = uv[i];
    }
    // ---- prefetch all G rows' masks (as bytes) ----
    if (tid < 96) {
        int t = tid >> 5, node = tid & 31;
        #pragma unroll
        for (int g = 0; g < G; ++g)
            mvB[g * 96 + tid] = (unsigned char)(
                maskg[(size_t)t * NB * NNODES + (size_t)(b0 + g) * NNODES + node] ? 1 : 0);
    }

    // ---- initial stage: row b0 -> buffer 0 (DMA, swizzled source) ----
    stage_row(hg + (size_t)b0 * (NNODES * DIM), hL, tid);
    __syncthreads();    // drains vmcnt(0)+lgkmcnt(0): buf0, uvL, mvB all ready

    float gr[G][TT];    // combine accumulators: 12 scalars, statically indexed

    #pragma unroll
    for (int g = 0; g < G; ++g) {
        const float* hb = hL + (g & 1) * (NNODES * DIM);

        // ---- issue DMA for row g+1 into the other buffer (waited at end of iter) ----
        if (g + 1 < G)
            stage_row(hg + (size_t)(b0 + g + 1) * (NNODES * DIM),
                      hL + ((g + 1) & 1) * (NNODES * DIM), tid);

        // ---- phase 1: 105 dots as (t, n-pair, d-quarter) tasks, u/v from uvL ----
        if (tid < 228) {
            const float4* hb4 = (const float4*)hb;
            if (tid < 192) {
                int task4 = tid >> 2;
                int t  = task4 >> 4;                 // == tid>>6, wave-uniform row
                int n0 = (task4 & 15) * 2;
                const float4* up = (const float4*)&uvL[(9 + t) * USTR];
                float a0 = 0.f, a1 = 0.f;
                #pragma unroll
                for (int k = 0; k < 8; ++k) {
                    int c = dq + 4 * k;
                    float4 x0 = hb4[swz_slot(n0,     c)];
                    float4 x1 = hb4[swz_slot(n0 + 1, c)];
                    float4 u  = up[c];
                    a0 += x0.x*u.x + x0.y*u.y + x0.z*u.z + x0.w*u.w;
                    a1 += x1.x*u.x + x1.y*u.y + x1.z*u.z + x1.w*u.w;
                }
                a0 += __shfl_xor(a0, 1, 64); a0 += __shfl_xor(a0, 2, 64);
                a1 += __shfl_xor(a1, 1, 64); a1 += __shfl_xor(a1, 2, 64);
                if (dq == 0) { sNbT[n0 * 4 + t] = a0; sNbT[(n0 + 1) * 4 + t] = a1; }
            } else {
                int e = (tid - 192) >> 2;   // 0..8, groups of 4 lanes (4-aligned, shfl-safe)
                const float4* up = (const float4*)&uvL[e * USTR];
                float a = 0.f;
                #pragma unroll
                for (int k = 0; k < 8; ++k) {
                    int c = dq + 4 * k;
                    float4 x = hb4[c];      // row 0: swizzle is identity
                    float4 u = up[c];
                    a += x.x*u.x + x.y*u.y + x.z*u.z + x.w*u.w;
                }
                a += __shfl_xor(a, 1, 64); a += __shfl_xor(a, 2, 64);
                if (dq == 0) sTop[e] = a;
            }
        }
        lds_barrier();

        // ---- phase 2: masked softmax (ally and opp separate) -> weights in-place in sNbT ----
        int wv = tid >> 6;
        if (wv == 0) {
            // ally: (j,n), 45 lanes; i collapsed (3 exps/lane)
            int lane = tid;
            bool act = lane < 45;
            int j = act ? lane / 15 : 0;
            int n = act ? lane % 15 : 0;
            int mk = 1; float sv = 0.f;
            if (act) {
                mk = mvB[g * 96 + j * 32 + 1 + n];
                sv = sNbT[(1 + n) * 4 + j];
            }
            float e0 = sTop[0 + j] + sv;
            float e1 = sTop[3 + j] + sv;
            float e2 = sTop[6 + j] + sv;
            bool live = act && (mk == 0);
            float lm = live ? fmaxf(e0, fmaxf(e1, e2)) : -__builtin_inff();
            #pragma unroll
            for (int off = 32; off; off >>= 1) lm = fmaxf(lm, __shfl_xor(lm, off, 64));
            float es = live ? (expf(e0 - lm) + expf(e1 - lm) + expf(e2 - lm)) : 0.f;
            float Z = es;
            #pragma unroll
            for (int off = 32; off; off >>= 1) Z += __shfl_xor(Z, off, 64);
            float w = (live && Z > 0.f) ? es / Z : 0.f;
            if (act) sNbT[(1 + n) * 4 + j] = w;
        } else if (wv == 1) {
            // opp: (j,n), 48 lanes
            int lane = tid - 64;
            bool act = lane < 48;
            int j = act ? (lane >> 4) : 0;
            int n = act ? (lane & 15) : 0;
            int mk = 1; float sv = 0.f;
            if (act) {
                mk = mvB[g * 96 + j * 32 + 16 + n];
                sv = sNbT[(16 + n) * 4 + j];
            }
            float e0 = sTop[0 + j] + sv;
            float e1 = sTop[3 + j] + sv;
            float e2 = sTop[6 + j] + sv;
            bool live = act && (mk == 0);
            float lm = live ? fmaxf(e0, fmaxf(e1, e2)) : -__builtin_inff();
            #pragma unroll
            for (int off = 32; off; off >>= 1) lm = fmaxf(lm, __shfl_xor(lm, off, 64));
            float es = live ? (expf(e0 - lm) + expf(e1 - lm) + expf(e2 - lm)) : 0.f;
            float Z = es;
            #pragma unroll
            for (int off = 32; off; off >>= 1) Z += __shfl_xor(Z, off, 64);
            float w = (live && Z > 0.f) ? es / Z : 0.f;
            if (act) sNbT[(16 + n) * 4 + j] = w;
        } else if (wv == 2) {
            int lane = tid - 128;
            if (lane < 3)
                sNbT[0 * 4 + lane] = mvB[g * 96 + lane * 32 + 0] ? 1.f : 0.f; // self: True -> included
        }
        lds_barrier();

        // ---- combine into registers: gr[g][t] for d = tid; weights via b128 broadcast ----
        if (tid < 128) {
            int d = tid;
            int chi = d >> 2, clo = d & 3;
            const float4* wq4 = (const float4*)sNbT;
            float a0 = 0.f, a1 = 0.f, a2 = 0.f;
            #pragma unroll
            for (int n = 0; n < NNODES; ++n) {
                float hv = hb[n * DIM + ((chi ^ (n & 7)) << 2) + clo];
                float4 w = wq4[n];          // wave-uniform -> b128 broadcast, 1 inst / 3 weights
                a0 += w.x * hv;
                a1 += w.y * hv;
                a2 += w.z * hv;
            }
            gr[g][0] = a0; gr[g][1] = a1; gr[g][2] = a2;
        }

        // ---- end of iter: wait for prefetch DMA + all LDS ops, then barrier ----
        asm volatile("s_waitcnt vmcnt(0) lgkmcnt(0)" ::: "memory");
        __builtin_amdgcn_s_barrier();
    }

    // ---- dump gr into dead hL buffer 0: gA[g*384 + t*128 + d] (floats 0..1535) ----
    if (tid < 128) {
        #pragma unroll
        for (int g = 0; g < G; ++g) {
            hL[g * 384 + 0 * 128 + tid] = gr[g][0];
            hL[g * 384 + 1 * 128 + tid] = gr[g][1];
            hL[g * 384 + 2 * 128 + tid] = gr[g][2];
        }
    }
    __syncthreads();

    // ---- epilogue: out[b0+g][h] = sum_t sum_d gA[g][t][d] * W[t][d][h] ----
    // 256 threads = 32 h-quads x 8 d-groups of 16; W streamed once per block (float4);
    // gA read as b128 (4 d's at a time).
    {
        int hq  = tid & 31;          // h0 = 4*hq
        int dq8 = tid >> 5;          // 0..7
        const float4* gA4 = (const float4*)hL;   // gA[g][t][d] float4 slot = g*96 + t*32 + d/4
        float4 acc[G];
        #pragma unroll
        for (int g = 0; g < G; ++g) acc[g] = make_float4(0.f, 0.f, 0.f, 0.f);
        #pragma unroll
        for (int t = 0; t < TT; ++t) {
            const float4* wb = (const float4*)(Wg + ((size_t)t * DIM + dq8 * 16) * HID) + hq;
            #pragma unroll
            for (int dp = 0; dp < 4; ++dp) {
                float4 w0 = wb[(dp * 4 + 0) * 32];
                float4 w1 = wb[(dp * 4 + 1) * 32];
                float4 w2 = wb[(dp * 4 + 2) * 32];
                float4 w3 = wb[(dp * 4 + 3) * 32];
                #pragma unroll
                for (int g = 0; g < G; ++g) {
                    float4 gv = gA4[g * 96 + t * 32 + dq8 * 4 + dp];  // b128 broadcast
                    acc[g].x += gv.x * w0.x + gv.y * w1.x + gv.z * w2.x + gv.w * w3.x;
                    acc[g].y += gv.x * w0.y + gv.y * w1.y + gv.z * w2.y + gv.w * w3.y;
                    acc[g].z += gv.x * w0.z + gv.y * w1.z + gv.z * w2.z + gv.w * w3.z;
                    acc[g].w += gv.x * w0.w + gv.y * w1.w + gv.z * w2.w + gv.w * w3.w;
                }
            }
        }
        // partials into hL floats 2048..6143 (float4 slot (dq8*4+g)*32 + hq)
        float4* pL4 = (float4*)(hL + 2048);
        #pragma unroll
        for (int g = 0; g < G; ++g)
            pL4[(dq8 * 4 + g) * 32 + hq] = acc[g];
    }
    __syncthreads();

    // ---- final: reduce 8 partials (b128), ELU, float4 store ----
    if (tid < 128) {
        int g = tid >> 5, q = tid & 31;
        const float4* pL4 = (const float4*)(hL + 2048);
        float4 s = make_float4(0.f, 0.f, 0.f, 0.f);
        #pragma unroll
        for (int p = 0; p < 8; ++p) {
            float4 v = pL4[p * 128 + g * 32 + q];
            s.x += v.x; s.y += v.y; s.z += v.z; s.w += v.w;
        }
        s.x = (s.x > 0.f) ? s.x : expm1f(s.x);
        s.y = (s.y > 0.f) ? s.y : expm1f(s.y);
        s.z = (s.z > 0.f) ? s.z : expm1f(s.z);
        s.w = (s.w > 0.f) ? s.w : expm1f(s.w);
        ((float4*)outg)[(size_t)(b0 + g) * 32 + q] = s;
    }
}

extern "C" void kernel_launch(void* const* d_in, const int* in_sizes, int n_in,
                              void* d_out, int out_size, void* d_ws, size_t ws_size,
                              hipStream_t stream) {
    const float* hg    = (const float*)d_in[0];    // h (B,32,128) fp32
    const int*   maskg = (const int*)d_in[1];      // ALL_TYPE_MASK (3,B,32) 4-byte words
    // d_in[2]=num_ally, d_in[3]=num_opp, d_in[4]=self_type (fixed)
    const float* Wg    = (const float*)d_in[5];    // W (3,128,128) fp32
    const float* ag    = (const float*)d_in[6];    // a (3,256,1) fp32
    float* uv = (float*)d_ws;                      // 12*128 fp32 scratch (validated)
    float* outg = (float*)d_out;                   // fp32 output

    gat_prep<<<12, 128, 0, stream>>>(Wg, ag, uv);
    gat_main<<<NBLK, 256, 0, stream>>>(hg, maskg, Wg, uv, outg);
}

// Round 8
// 227.426 us; speedup vs baseline: 1.2408x; 1.0440x over previous
//
#include <hip/hip_runtime.h>
#include <math.h>

#define NB 8192
#define G 4                 // batch rows per block
#define NBLK (NB / G)
#define NNODES 32
#define TT 3
#define DIM 128
#define HID 128

// Kernel 1: uv[e][d], e<9: u[i=e/3][j=e%3][d] = W[i] row d . a_top[j]
//           e=9+t:    v[t][d]                 = W[t] row d . a_bot[t]
// Identical for all batch rows -> compute ONCE into d_ws (ws validated earlier).
__global__ __launch_bounds__(128) void gat_prep(
    const float* __restrict__ Wg,   // (3,128,128) fp32
    const float* __restrict__ ag,   // (3,256,1)   fp32
    float* __restrict__ uv)         // (12,128)    fp32
{
    int e = blockIdx.x, d = threadIdx.x;
    int wi, aoff;
    if (e < 9) { wi = e / 3; aoff = (e % 3) * 2 * HID; }        // a_top[j]
    else       { wi = e - 9; aoff = wi * 2 * HID + HID; }       // a_bot[t]
    const float* wrow = Wg + wi * DIM * HID + d * HID;
    const float* arow = ag + aoff;
    float acc = 0.f;
    #pragma unroll 16
    for (int h = 0; h < HID; ++h) acc += wrow[h] * arow[h];
    uv[e * DIM + d] = acc;
}

// Chunk (n, c) of a 32x128 fp32 row-tile lives at float4-slot n*32 + (c ^ (n&7)).
// XOR is an involution: global_load_lds writes LINEAR dest slots while each lane
// reads the pre-swizzled global source chunk; LDS readers apply the same XOR.
__device__ __forceinline__ int swz_slot(int n, int c) { return n * 32 + (c ^ (n & 7)); }

// LDS-only barrier: drains lgkmcnt, leaves vmcnt alone.
__device__ __forceinline__ void lds_barrier() {
    asm volatile("s_waitcnt lgkmcnt(0)" ::: "memory");
    __builtin_amdgcn_s_barrier();
}
// DMA barrier: drains vmcnt (global_load_lds completion), then block barrier.
__device__ __forceinline__ void vm_barrier() {
    asm volatile("s_waitcnt vmcnt(0)" ::: "memory");
    __builtin_amdgcn_s_barrier();
}

// Stage one 16 KB h-row into LDS via direct global->LDS DMA (no VGPR staging).
// Linear LDS dest (wave-uniform base + lane*16), per-lane pre-swizzled source.
__device__ __forceinline__ void stage_row(const float* __restrict__ hrow,
                                          float* lbuf, int tid) {
    const int wv = tid >> 6, lane = tid & 63;
    #pragma unroll
    for (int k = 0; k < 4; ++k) {
        int s = wv * 256 + k * 64 + lane;          // linear dest float4-slot
        int n = s >> 5, c = s & 31;
        const float4* g = (const float4*)hrow + (n * 32 + (c ^ (n & 7)));
        float4* l = (float4*)lbuf + (wv * 256 + k * 64);   // wave-uniform base
        __builtin_amdgcn_global_load_lds(
            (const __attribute__((address_space(1))) void*)g,
            (__attribute__((address_space(3))) void*)l, 16, 0, 0);
    }
}

// (256,4) is the proven no-spill configuration for this loop body (VGPR 60).
// LDS diet: single-buffer hL + arena overlay + bitpacked masks = 23,024 B
// declared -> 23,040 after 512-B rounding -> 7 blocks/CU (28 waves) instead of 4.
// Occupancy is the lever: rounds 4-7 showed dur tracks resident waves, not
// instruction count (latency/barrier-bound; no pipe saturated).
__global__ __launch_bounds__(256, 4) void gat_main(
    const float* __restrict__ hg,     // (B,32,128) fp32
    const int* __restrict__ maskg,    // (3,B,32) 4-byte bool words
    const float* __restrict__ Wg,     // (3,128,128) fp32
    const float* __restrict__ uv,     // (12,128) fp32 (from d_ws)
    float* __restrict__ outg)         // (B,128) fp32
{
    // arena: loop phase  [0..4095] hL (swizzled h row) | [4096..5631] uvL
    //        post-loop   [0..1535] gA | [1536..5631] epilogue partials
    __shared__ __align__(16) float arena[5632];           // 22,528 B
    __shared__ float sTop[16];                            // [3i+j]
    __shared__ float sNb[TT * NNODES];                    // scores -> weights in-place
    __shared__ unsigned int mvW[G * TT];                  // bitmask per (g,t), bit = node
    // declared total 23,024 B -> 7 blocks/CU

    const int tid = threadIdx.x;
    const int b0 = blockIdx.x * G;
    const int dq = tid & 3;
    float* hL  = arena;
    float* uvL = arena + 4096;

    // ---- stage uv into LDS (1536 elems, contiguous) ----
    #pragma unroll
    for (int k = 0; k < 6; ++k) {
        int i = tid + k * 256;
        uvL[i] = uv[i];
    }
    // ---- masks: 12 threads each pack one (g,t) row of 32 bools into a word ----
    if (tid < G * TT) {
        int g = tid / TT, t = tid % TT;
        const int4* m4 = (const int4*)(maskg + (size_t)t * NB * NNODES
                                             + (size_t)(b0 + g) * NNODES);
        unsigned int m = 0;
        #pragma unroll
        for (int q = 0; q < 8; ++q) {
            int4 v = m4[q];
            m |= (v.x ? 1u : 0u) << (4 * q + 0);
            m |= (v.y ? 1u : 0u) << (4 * q + 1);
            m |= (v.z ? 1u : 0u) << (4 * q + 2);
            m |= (v.w ? 1u : 0u) << (4 * q + 3);
        }
        mvW[g * TT + t] = m;
    }
    __syncthreads();    // uvL + mvW visible to all waves

    float gr[G][TT];    // combine accumulators: 12 scalars, statically indexed (no-spill proven)

    #pragma unroll
    for (int g = 0; g < G; ++g) {
        // ---- stage h[b0+g] into the single buffer; wait in-iteration ----
        stage_row(hg + (size_t)(b0 + g) * (NNODES * DIM), hL, tid);
        vm_barrier();   // each wave drains its own DMA, barrier makes all landed

        // ---- phase 1: 105 dots as (t, n-pair, d-quarter) tasks, u/v from uvL ----
        if (tid < 228) {
            const float4* hb4 = (const float4*)hL;
            if (tid < 192) {
                int task4 = tid >> 2;
                int t  = task4 >> 4;                 // == tid>>6, wave-uniform row
                int n0 = (task4 & 15) * 2;
                const float4* up = (const float4*)(uvL + (9 + t) * DIM);
                float a0 = 0.f, a1 = 0.f;
                #pragma unroll
                for (int k = 0; k < 8; ++k) {
                    int c = dq + 4 * k;
                    float4 x0 = hb4[swz_slot(n0,     c)];
                    float4 x1 = hb4[swz_slot(n0 + 1, c)];
                    float4 u  = up[c];
                    a0 += x0.x*u.x + x0.y*u.y + x0.z*u.z + x0.w*u.w;
                    a1 += x1.x*u.x + x1.y*u.y + x1.z*u.z + x1.w*u.w;
                }
                a0 += __shfl_xor(a0, 1, 64); a0 += __shfl_xor(a0, 2, 64);
                a1 += __shfl_xor(a1, 1, 64); a1 += __shfl_xor(a1, 2, 64);
                if (dq == 0) { sNb[t * 32 + n0] = a0; sNb[t * 32 + n0 + 1] = a1; }
            } else {
                int e = (tid - 192) >> 2;   // 0..8, groups of 4 lanes (4-aligned, shfl-safe)
                const float4* up = (const float4*)(uvL + e * DIM);
                float a = 0.f;
                #pragma unroll
                for (int k = 0; k < 8; ++k) {
                    int c = dq + 4 * k;
                    float4 x = hb4[c];      // row 0: swizzle is identity
                    float4 u = up[c];
                    a += x.x*u.x + x.y*u.y + x.z*u.z + x.w*u.w;
                }
                a += __shfl_xor(a, 1, 64); a += __shfl_xor(a, 2, 64);
                if (dq == 0) sTop[e] = a;
            }
        }
        lds_barrier();

        // ---- phase 2: masked softmax (ally and opp separate) -> weights in-place in sNb ----
        int wv = tid >> 6;
        if (wv == 0) {
            // ally: (j,n), 45 lanes; i collapsed (3 exps/lane)
            int lane = tid;
            bool act = lane < 45;
            int j = act ? lane / 15 : 0;
            int n = act ? lane % 15 : 0;
            unsigned int mk = 1; float sv = 0.f;
            if (act) {
                mk = (mvW[g * TT + j] >> (1 + n)) & 1u;
                sv = sNb[j * 32 + 1 + n];
            }
            float e0 = sTop[0 + j] + sv;
            float e1 = sTop[3 + j] + sv;
            float e2 = sTop[6 + j] + sv;
            bool live = act && (mk == 0);
            float lm = live ? fmaxf(e0, fmaxf(e1, e2)) : -__builtin_inff();
            #pragma unroll
            for (int off = 32; off; off >>= 1) lm = fmaxf(lm, __shfl_xor(lm, off, 64));
            float es = live ? (expf(e0 - lm) + expf(e1 - lm) + expf(e2 - lm)) : 0.f;
            float Z = es;
            #pragma unroll
            for (int off = 32; off; off >>= 1) Z += __shfl_xor(Z, off, 64);
            float w = (live && Z > 0.f) ? es / Z : 0.f;
            if (act) sNb[j * 32 + 1 + n] = w;
        } else if (wv == 1) {
            // opp: (j,n), 48 lanes
            int lane = tid - 64;
            bool act = lane < 48;
            int j = act ? (lane >> 4) : 0;
            int n = act ? (lane & 15) : 0;
            unsigned int mk = 1; float sv = 0.f;
            if (act) {
                mk = (mvW[g * TT + j] >> (16 + n)) & 1u;
                sv = sNb[j * 32 + 16 + n];
            }
            float e0 = sTop[0 + j] + sv;
            float e1 = sTop[3 + j] + sv;
            float e2 = sTop[6 + j] + sv;
            bool live = act && (mk == 0);
            float lm = live ? fmaxf(e0, fmaxf(e1, e2)) : -__builtin_inff();
            #pragma unroll
            for (int off = 32; off; off >>= 1) lm = fmaxf(lm, __shfl_xor(lm, off, 64));
            float es = live ? (expf(e0 - lm) + expf(e1 - lm) + expf(e2 - lm)) : 0.f;
            float Z = es;
            #pragma unroll
            for (int off = 32; off; off >>= 1) Z += __shfl_xor(Z, off, 64);
            float w = (live && Z > 0.f) ? es / Z : 0.f;
            if (act) sNb[j * 32 + 16 + n] = w;
        } else if (wv == 2) {
            int lane = tid - 128;
            if (lane < 3)
                sNb[lane * 32 + 0] = (mvW[g * TT + lane] & 1u) ? 1.f : 0.f; // self: True -> included
        }
        lds_barrier();

        // ---- combine into registers: gr[g][t] for d = tid (sNb reads are broadcasts) ----
        if (tid < 128) {
            int d = tid;
            int chi = d >> 2, clo = d & 3;
            float a0 = 0.f, a1 = 0.f, a2 = 0.f;
            #pragma unroll
            for (int n = 0; n < NNODES; ++n) {
                float hv = hL[n * DIM + ((chi ^ (n & 7)) << 2) + clo];
                a0 += sNb[n] * hv;
                a1 += sNb[NNODES + n] * hv;
                a2 += sNb[2 * NNODES + n] * hv;
            }
            gr[g][0] = a0; gr[g][1] = a1; gr[g][2] = a2;
        }
        lds_barrier();  // all hL reads done before next iteration's stage overwrites
    }

    // ---- dump gr: gA[g*384 + t*128 + d] = arena floats 0..1535 ----
    if (tid < 128) {
        #pragma unroll
        for (int g = 0; g < G; ++g) {
            arena[g * 384 + 0 * 128 + tid] = gr[g][0];
            arena[g * 384 + 1 * 128 + tid] = gr[g][1];
            arena[g * 384 + 2 * 128 + tid] = gr[g][2];
        }
    }
    __syncthreads();

    // ---- epilogue: out[b0+g][h] = sum_t sum_d gA[g][t][d] * W[t][d][h] ----
    // 256 threads = 32 h-quads x 8 d-groups of 16; W streamed once per block (float4).
    {
        int hq  = tid & 31;          // h0 = 4*hq
        int dq8 = tid >> 5;          // 0..7
        float4 acc[G];
        #pragma unroll
        for (int g = 0; g < G; ++g) acc[g] = make_float4(0.f, 0.f, 0.f, 0.f);
        #pragma unroll
        for (int t = 0; t < TT; ++t) {
            const float* wbase = Wg + ((size_t)t * DIM + dq8 * 16) * HID + 4 * hq;
            const float* gbase = arena + t * 128 + dq8 * 16;
            #pragma unroll 4
            for (int dd = 0; dd < 16; ++dd) {
                float4 wq = *(const float4*)(wbase + dd * HID);
                #pragma unroll
                for (int g = 0; g < G; ++g) {
                    float gv = gbase[g * 384 + dd];   // near-uniform -> LDS broadcast
                    acc[g].x += gv * wq.x;
                    acc[g].y += gv * wq.y;
                    acc[g].z += gv * wq.z;
                    acc[g].w += gv * wq.w;
                }
            }
        }
        // partials into arena floats 1536..5631
        float* pL = arena + 1536;
        #pragma unroll
        for (int g = 0; g < G; ++g)
            *(float4*)&pL[(dq8 * G + g) * DIM + 4 * hq] = acc[g];
    }
    __syncthreads();

    // ---- final: reduce 8 partials, ELU, fp32 store ----
    #pragma unroll
    for (int r = 0; r < 2; ++r) {
        int idx = tid + r * 256;        // 0..511 -> (g, h)
        int g = idx >> 7, h = idx & 127;
        const float* pL = arena + 1536;
        float s = 0.f;
        #pragma unroll
        for (int p = 0; p < 8; ++p) s += pL[p * 512 + idx];
        float rr = (s > 0.f) ? s : expm1f(s);
        outg[(size_t)(b0 + g) * DIM + h] = rr;
    }
}

extern "C" void kernel_launch(void* const* d_in, const int* in_sizes, int n_in,
                              void* d_out, int out_size, void* d_ws, size_t ws_size,
                              hipStream_t stream) {
    const float* hg    = (const float*)d_in[0];    // h (B,32,128) fp32
    const int*   maskg = (const int*)d_in[1];      // ALL_TYPE_MASK (3,B,32) 4-byte words
    // d_in[2]=num_ally, d_in[3]=num_opp, d_in[4]=self_type (fixed)
    const float* Wg    = (const float*)d_in[5];    // W (3,128,128) fp32
    const float* ag    = (const float*)d_in[6];    // a (3,256,1) fp32
    float* uv = (float*)d_ws;                      // 12*128 fp32 scratch (validated)
    float* outg = (float*)d_out;                   // fp32 output

    gat_prep<<<12, 128, 0, stream>>>(Wg, ag, uv);
    gat_main<<<NBLK, 256, 0, stream>>>(hg, maskg, Wg, uv, outg);
}

// Round 9
// 224.666 us; speedup vs baseline: 1.2561x; 1.0123x over previous
//
#include <hip/hip_runtime.h>
#include <math.h>

#define NB 8192
#define G 4                 // batch rows per block
#define NBLK (NB / G)
#define NNODES 32
#define TT 3
#define DIM 128
#define HID 128

// Kernel 1: uv[e][d], e<9: u[i=e/3][j=e%3][d] = W[i] row d . a_top[j]
//           e=9+t:    v[t][d]                 = W[t] row d . a_bot[t]
// Identical for all batch rows -> compute ONCE into d_ws (ws validated earlier).
__global__ __launch_bounds__(128) void gat_prep(
    const float* __restrict__ Wg,   // (3,128,128) fp32
    const float* __restrict__ ag,   // (3,256,1)   fp32
    float* __restrict__ uv)         // (12,128)    fp32
{
    int e = blockIdx.x, d = threadIdx.x;
    int wi, aoff;
    if (e < 9) { wi = e / 3; aoff = (e % 3) * 2 * HID; }        // a_top[j]
    else       { wi = e - 9; aoff = wi * 2 * HID + HID; }       // a_bot[t]
    const float* wrow = Wg + wi * DIM * HID + d * HID;
    const float* arow = ag + aoff;
    float acc = 0.f;
    #pragma unroll 16
    for (int h = 0; h < HID; ++h) acc += wrow[h] * arow[h];
    uv[e * DIM + d] = acc;
}

// Chunk (n, c) of a 32x128 fp32 row-tile lives at float4-slot n*32 + (c ^ (n&7)).
// XOR is an involution: global_load_lds writes LINEAR dest slots while each lane
// reads the pre-swizzled global source chunk; LDS readers apply the same XOR.
__device__ __forceinline__ int swz_slot(int n, int c) { return n * 32 + (c ^ (n & 7)); }

// LDS-only barrier: drains lgkmcnt, leaves vmcnt alone.
__device__ __forceinline__ void lds_barrier() {
    asm volatile("s_waitcnt lgkmcnt(0)" ::: "memory");
    __builtin_amdgcn_s_barrier();
}
// DMA barrier: drains vmcnt (global_load_lds completion), then block barrier.
__device__ __forceinline__ void vm_barrier() {
    asm volatile("s_waitcnt vmcnt(0)" ::: "memory");
    __builtin_amdgcn_s_barrier();
}

// Stage one 16 KB h-row into LDS via direct global->LDS DMA (no VGPR staging).
// Linear LDS dest (wave-uniform base + lane*16), per-lane pre-swizzled source.
__device__ __forceinline__ void stage_row(const float* __restrict__ hrow,
                                          float* lbuf, int tid) {
    const int wv = tid >> 6, lane = tid & 63;
    #pragma unroll
    for (int k = 0; k < 4; ++k) {
        int s = wv * 256 + k * 64 + lane;          // linear dest float4-slot
        int n = s >> 5, c = s & 31;
        const float4* g = (const float4*)hrow + (n * 32 + (c ^ (n & 7)));
        float4* l = (float4*)lbuf + (wv * 256 + k * 64);   // wave-uniform base
        __builtin_amdgcn_global_load_lds(
            (const __attribute__((address_space(1))) void*)g,
            (__attribute__((address_space(3))) void*)l, 16, 0, 0);
    }
}

// (256,4): empirical VGPR wall at 64 for this kernel family; r8 measured 56.
// This round's additions are engineered to stay <=64 (combine: +1 transient
// float4; epilogue: one W float4 live at a time). WRITE_SIZE is the spill
// tripwire (clean = ~4096 KB).
__global__ __launch_bounds__(256, 4) void gat_main(
    const float* __restrict__ hg,     // (B,32,128) fp32
    const int* __restrict__ maskg,    // (3,B,32) 4-byte bool words
    const float* __restrict__ Wg,     // (3,128,128) fp32
    const float* __restrict__ uv,     // (12,128) fp32 (from d_ws)
    float* __restrict__ outg)         // (B,128) fp32
{
    // arena: loop phase  [0..4095] hL (swizzled h row) | [4096..5631] uvL
    //        post-loop   [0..1535] gA | [1536..5631] epilogue partials
    __shared__ __align__(16) float arena[5632];           // 22,528 B
    // sNbT[n] = (w[t=0], w[t=1], w[t=2], aux); aux[e=0..8] holds the sTop dots.
    // Phase1 writes comps 0-2 (n-dots) and comp 3 (e-dots, nodes 0-8);
    // combine reads .xyz only -> aux garbage never consumed.
    __shared__ __align__(16) float sNbT[NNODES * 4];      // 512 B
    __shared__ unsigned int mvW[G * TT];                  // bitmask per (g,t), bit = node
    // declared 23,088 B -> 23,296 after 256-B granule -> 7 blocks/CU

    const int tid = threadIdx.x;
    const int b0 = blockIdx.x * G;
    const int dq = tid & 3;
    float* hL  = arena;
    float* uvL = arena + 4096;

    // ---- stage uv into LDS (1536 elems, contiguous) ----
    #pragma unroll
    for (int k = 0; k < 6; ++k) {
        int i = tid + k * 256;
        uvL[i] = uv[i];
    }
    // ---- masks: 12 threads each pack one (g,t) row of 32 bools into a word ----
    if (tid < G * TT) {
        int g = tid / TT, t = tid % TT;
        const int4* m4 = (const int4*)(maskg + (size_t)t * NB * NNODES
                                             + (size_t)(b0 + g) * NNODES);
        unsigned int m = 0;
        #pragma unroll
        for (int q = 0; q < 8; ++q) {
            int4 v = m4[q];
            m |= (v.x ? 1u : 0u) << (4 * q + 0);
            m |= (v.y ? 1u : 0u) << (4 * q + 1);
            m |= (v.z ? 1u : 0u) << (4 * q + 2);
            m |= (v.w ? 1u : 0u) << (4 * q + 3);
        }
        mvW[g * TT + t] = m;
    }
    __syncthreads();    // uvL + mvW visible to all waves

    float gr[G][TT];    // combine accumulators: 12 scalars, statically indexed (no-spill proven)

    #pragma unroll
    for (int g = 0; g < G; ++g) {
        // ---- stage h[b0+g] into the single buffer; wait in-iteration ----
        stage_row(hg + (size_t)(b0 + g) * (NNODES * DIM), hL, tid);
        vm_barrier();   // each wave drains its own DMA, barrier makes all landed

        // ---- phase 1: 105 dots as (t, n-pair, d-quarter) tasks, u/v from uvL ----
        if (tid < 228) {
            const float4* hb4 = (const float4*)hL;
            if (tid < 192) {
                int task4 = tid >> 2;
                int t  = task4 >> 4;                 // == tid>>6, wave-uniform row
                int n0 = (task4 & 15) * 2;
                const float4* up = (const float4*)(uvL + (9 + t) * DIM);
                float a0 = 0.f, a1 = 0.f;
                #pragma unroll
                for (int k = 0; k < 8; ++k) {
                    int c = dq + 4 * k;
                    float4 x0 = hb4[swz_slot(n0,     c)];
                    float4 x1 = hb4[swz_slot(n0 + 1, c)];
                    float4 u  = up[c];
                    a0 += x0.x*u.x + x0.y*u.y + x0.z*u.z + x0.w*u.w;
                    a1 += x1.x*u.x + x1.y*u.y + x1.z*u.z + x1.w*u.w;
                }
                a0 += __shfl_xor(a0, 1, 64); a0 += __shfl_xor(a0, 2, 64);
                a1 += __shfl_xor(a1, 1, 64); a1 += __shfl_xor(a1, 2, 64);
                if (dq == 0) { sNbT[n0 * 4 + t] = a0; sNbT[(n0 + 1) * 4 + t] = a1; }
            } else {
                int e = (tid - 192) >> 2;   // 0..8, groups of 4 lanes (4-aligned, shfl-safe)
                const float4* up = (const float4*)(uvL + e * DIM);
                float a = 0.f;
                #pragma unroll
                for (int k = 0; k < 8; ++k) {
                    int c = dq + 4 * k;
                    float4 x = hb4[c];      // row 0: swizzle is identity
                    float4 u = up[c];
                    a += x.x*u.x + x.y*u.y + x.z*u.z + x.w*u.w;
                }
                a += __shfl_xor(a, 1, 64); a += __shfl_xor(a, 2, 64);
                if (dq == 0) sNbT[e * 4 + 3] = a;   // sTop[e] in aux slot
            }
        }
        lds_barrier();

        // ---- phase 2: masked softmax (ally and opp separate) -> weights in-place in sNbT ----
        int wv = tid >> 6;
        if (wv == 0) {
            // ally: (j,n), 45 lanes; i collapsed (3 exps/lane)
            int lane = tid;
            bool act = lane < 45;
            int j = act ? lane / 15 : 0;
            int n = act ? lane % 15 : 0;
            unsigned int mk = 1; float sv = 0.f;
            if (act) {
                mk = (mvW[g * TT + j] >> (1 + n)) & 1u;
                sv = sNbT[(1 + n) * 4 + j];
            }
            float e0 = sNbT[(0 + j) * 4 + 3] + sv;   // sTop[j]
            float e1 = sNbT[(3 + j) * 4 + 3] + sv;   // sTop[3+j]
            float e2 = sNbT[(6 + j) * 4 + 3] + sv;   // sTop[6+j]
            bool live = act && (mk == 0);
            float lm = live ? fmaxf(e0, fmaxf(e1, e2)) : -__builtin_inff();
            #pragma unroll
            for (int off = 32; off; off >>= 1) lm = fmaxf(lm, __shfl_xor(lm, off, 64));
            float es = live ? (expf(e0 - lm) + expf(e1 - lm) + expf(e2 - lm)) : 0.f;
            float Z = es;
            #pragma unroll
            for (int off = 32; off; off >>= 1) Z += __shfl_xor(Z, off, 64);
            float w = (live && Z > 0.f) ? es / Z : 0.f;
            if (act) sNbT[(1 + n) * 4 + j] = w;
        } else if (wv == 1) {
            // opp: (j,n), 48 lanes
            int lane = tid - 64;
            bool act = lane < 48;
            int j = act ? (lane >> 4) : 0;
            int n = act ? (lane & 15) : 0;
            unsigned int mk = 1; float sv = 0.f;
            if (act) {
                mk = (mvW[g * TT + j] >> (16 + n)) & 1u;
                sv = sNbT[(16 + n) * 4 + j];
            }
            float e0 = sNbT[(0 + j) * 4 + 3] + sv;
            float e1 = sNbT[(3 + j) * 4 + 3] + sv;
            float e2 = sNbT[(6 + j) * 4 + 3] + sv;
            bool live = act && (mk == 0);
            float lm = live ? fmaxf(e0, fmaxf(e1, e2)) : -__builtin_inff();
            #pragma unroll
            for (int off = 32; off; off >>= 1) lm = fmaxf(lm, __shfl_xor(lm, off, 64));
            float es = live ? (expf(e0 - lm) + expf(e1 - lm) + expf(e2 - lm)) : 0.f;
            float Z = es;
            #pragma unroll
            for (int off = 32; off; off >>= 1) Z += __shfl_xor(Z, off, 64);
            float w = (live && Z > 0.f) ? es / Z : 0.f;
            if (act) sNbT[(16 + n) * 4 + j] = w;
        } else if (wv == 2) {
            int lane = tid - 128;
            if (lane < 3)
                sNbT[0 * 4 + lane] = (mvW[g * TT + lane] & 1u) ? 1.f : 0.f; // self: True -> included
        }
        lds_barrier();

        // ---- combine into registers: gr[g][t] for d = tid;
        //      weights via single b128 broadcast per node ----
        if (tid < 128) {
            int d = tid;
            int chi = d >> 2, clo = d & 3;
            const float4* wq4 = (const float4*)sNbT;
            float a0 = 0.f, a1 = 0.f, a2 = 0.f;
            #pragma unroll 8
            for (int n = 0; n < NNODES; ++n) {
                float hv = hL[n * DIM + ((chi ^ (n & 7)) << 2) + clo];
                float4 w = wq4[n];          // wave-uniform b128 broadcast (.xyz used)
                a0 += w.x * hv;
                a1 += w.y * hv;
                a2 += w.z * hv;
            }
            gr[g][0] = a0; gr[g][1] = a1; gr[g][2] = a2;
        }
        lds_barrier();  // all hL reads done before next iteration's stage / gr dump
    }

    // ---- dump gr: gA[g*384 + t*128 + d] = arena floats 0..1535 ----
    if (tid < 128) {
        #pragma unroll
        for (int g = 0; g < G; ++g) {
            arena[g * 384 + 0 * 128 + tid] = gr[g][0];
            arena[g * 384 + 1 * 128 + tid] = gr[g][1];
            arena[g * 384 + 2 * 128 + tid] = gr[g][2];
        }
    }
    __syncthreads();

    // ---- epilogue: out[b0+g][h] = sum_t sum_d gA[g][t][d] * W[t][d][h] ----
    // 256 threads = 32 h-quads x 8 d-groups of 16; gA as b128 (48 reads/thread);
    // W streamed float4, ONE live at a time across the g-unrolled FMAs.
    {
        int hq  = tid & 31;          // h0 = 4*hq
        int dq8 = tid >> 5;          // 0..7
        const float4* gA4 = (const float4*)arena;  // slot = g*96 + t*32 + d/4
        float4 acc0 = make_float4(0.f,0.f,0.f,0.f), acc1 = acc0, acc2 = acc0, acc3 = acc0;
        #pragma unroll
        for (int t = 0; t < TT; ++t) {
            const float4* wb = (const float4*)(Wg + ((size_t)t * DIM + dq8 * 16) * HID) + hq;
            #pragma unroll
            for (int dp = 0; dp < 4; ++dp) {
                int gs = t * 32 + dq8 * 4 + dp;
                float4 gv0 = gA4[0 * 96 + gs];
                float4 gv1 = gA4[1 * 96 + gs];
                float4 gv2 = gA4[2 * 96 + gs];
                float4 gv3 = gA4[3 * 96 + gs];
                float4 w;
                w = wb[(dp * 4 + 0) * 32];
                acc0.x += gv0.x*w.x; acc0.y += gv0.x*w.y; acc0.z += gv0.x*w.z; acc0.w += gv0.x*w.w;
                acc1.x += gv1.x*w.x; acc1.y += gv1.x*w.y; acc1.z += gv1.x*w.z; acc1.w += gv1.x*w.w;
                acc2.x += gv2.x*w.x; acc2.y += gv2.x*w.y; acc2.z += gv2.x*w.z; acc2.w += gv2.x*w.w;
                acc3.x += gv3.x*w.x; acc3.y += gv3.x*w.y; acc3.z += gv3.x*w.z; acc3.w += gv3.x*w.w;
                w = wb[(dp * 4 + 1) * 32];
                acc0.x += gv0.y*w.x; acc0.y += gv0.y*w.y; acc0.z += gv0.y*w.z; acc0.w += gv0.y*w.w;
                acc1.x += gv1.y*w.x; acc1.y += gv1.y*w.y; acc1.z += gv1.y*w.z; acc1.w += gv1.y*w.w;
                acc2.x += gv2.y*w.x; acc2.y += gv2.y*w.y; acc2.z += gv2.y*w.z; acc2.w += gv2.y*w.w;
                acc3.x += gv3.y*w.x; acc3.y += gv3.y*w.y; acc3.z += gv3.y*w.z; acc3.w += gv3.y*w.w;
                w = wb[(dp * 4 + 2) * 32];
                acc0.x += gv0.z*w.x; acc0.y += gv0.z*w.y; acc0.z += gv0.z*w.z; acc0.w += gv0.z*w.w;
                acc1.x += gv1.z*w.x; acc1.y += gv1.z*w.y; acc1.z += gv1.z*w.z; acc1.w += gv1.z*w.w;
                acc2.x += gv2.z*w.x; acc2.y += gv2.z*w.y; acc2.z += gv2.z*w.z; acc2.w += gv2.z*w.w;
                acc3.x += gv3.z*w.x; acc3.y += gv3.z*w.y; acc3.z += gv3.z*w.z; acc3.w += gv3.z*w.w;
                w = wb[(dp * 4 + 3) * 32];
                acc0.x += gv0.w*w.x; acc0.y += gv0.w*w.y; acc0.z += gv0.w*w.z; acc0.w += gv0.w*w.w;
                acc1.x += gv1.w*w.x; acc1.y += gv1.w*w.y; acc1.z += gv1.w*w.z; acc1.w += gv1.w*w.w;
                acc2.x += gv2.w*w.x; acc2.y += gv2.w*w.y; acc2.z += gv2.w*w.z; acc2.w += gv2.w*w.w;
                acc3.x += gv3.w*w.x; acc3.y += gv3.w*w.y; acc3.z += gv3.w*w.z; acc3.w += gv3.w*w.w;
            }
        }
        // partials into arena floats 1536..5631 (float4 slot (dq8*4+g)*32 + hq)
        float4* pL4 = (float4*)(arena + 1536);
        pL4[(dq8 * 4 + 0) * 32 + hq] = acc0;
        pL4[(dq8 * 4 + 1) * 32 + hq] = acc1;
        pL4[(dq8 * 4 + 2) * 32 + hq] = acc2;
        pL4[(dq8 * 4 + 3) * 32 + hq] = acc3;
    }
    __syncthreads();

    // ---- final: reduce 8 partials (b128), ELU, float4 store ----
    if (tid < 128) {
        int g = tid >> 5, q = tid & 31;
        const float4* pL4 = (const float4*)(arena + 1536);
        float4 s = make_float4(0.f, 0.f, 0.f, 0.f);
        #pragma unroll
        for (int p = 0; p < 8; ++p) {
            float4 v = pL4[p * 128 + g * 32 + q];
            s.x += v.x; s.y += v.y; s.z += v.z; s.w += v.w;
        }
        s.x = (s.x > 0.f) ? s.x : expm1f(s.x);
        s.y = (s.y > 0.f) ? s.y : expm1f(s.y);
        s.z = (s.z > 0.f) ? s.z : expm1f(s.z);
        s.w = (s.w > 0.f) ? s.w : expm1f(s.w);
        ((float4*)outg)[(size_t)(b0 + g) * 32 + q] = s;
    }
}

extern "C" void kernel_launch(void* const* d_in, const int* in_sizes, int n_in,
                              void* d_out, int out_size, void* d_ws, size_t ws_size,
                              hipStream_t stream) {
    const float* hg    = (const float*)d_in[0];    // h (B,32,128) fp32
    const int*   maskg = (const int*)d_in[1];      // ALL_TYPE_MASK (3,B,32) 4-byte words
    // d_in[2]=num_ally, d_in[3]=num_opp, d_in[4]=self_type (fixed)
    const float* Wg    = (const float*)d_in[5];    // W (3,128,128) fp32
    const float* ag    = (const float*)d_in[6];    // a (3,256,1) fp32
    float* uv = (float*)d_ws;                      // 12*128 fp32 scratch (validated)
    float* outg = (float*)d_out;                   // fp32 output

    gat_prep<<<12, 128, 0, stream>>>(Wg, ag, uv);
    gat_main<<<NBLK, 256, 0, stream>>>(hg, maskg, Wg, uv, outg);
}